// Round 1
// baseline (687.346 us; speedup 1.0000x reference)
//
#include <hip/hip_runtime.h>
#include <math.h>

// Problem constants (from reference): B=32, L=4096, H=1024
constexpr int B_ = 32;
constexpr int L_ = 4096;
constexpr int H_ = 1024;

// ---------------------------------------------------------------------------
// Kernel 1: v[b][h] = sum_g hidden[b][g] * W[g][h]   (v = h @ W, [32,1024])
// Split over g (GSPLIT chunks) for latency hiding; partials combined with
// device-scope f32 atomicAdd into v (v zeroed via hipMemsetAsync first).
// grid = (B, H/256, GSPLIT), block = 256, one output column per thread.
// ---------------------------------------------------------------------------
constexpr int GSPLIT = 8;
constexpr int GCHUNK = H_ / GSPLIT; // 128

__global__ __launch_bounds__(256) void vW_kernel(const float* __restrict__ hidden,
                                                 const float* __restrict__ W,
                                                 float* __restrict__ v) {
    const int b  = blockIdx.x;
    const int hc = blockIdx.y;
    const int gs = blockIdx.z;
    const int t  = threadIdx.x;
    const int h  = hc * 256 + t;

    __shared__ float hlds[GCHUNK];
    if (t < GCHUNK) hlds[t] = hidden[b * H_ + gs * GCHUNK + t];
    __syncthreads();

    const float* Wp = W + (size_t)(gs * GCHUNK) * H_ + h;
    float acc = 0.f;
#pragma unroll 16
    for (int g = 0; g < GCHUNK; ++g) {
        acc = fmaf(hlds[g], Wp[(size_t)g * H_], acc);  // coalesced across t
    }
    atomicAdd(&v[b * H_ + h], acc);
}

// ---------------------------------------------------------------------------
// Kernel 2: e[b][l] = dot(targets[b,l,:], v[b,:])
// The only HBM-heavy pass: streams targets (512 MiB) exactly once.
// One wave (64 lanes) per output row; 4 rows per 256-thread block.
// v[b] staged in LDS (4 KB), float4-vectorized loads (16 B/lane).
// grid = B*L/4 = 32768 blocks.
// ---------------------------------------------------------------------------
__global__ __launch_bounds__(256) void energy_kernel(const float* __restrict__ targets,
                                                     const float* __restrict__ v,
                                                     float* __restrict__ e) {
    const int blocksPerB = L_ / 4; // 1024
    const int b  = blockIdx.x / blocksPerB;
    const int lc = blockIdx.x % blocksPerB;
    const int t  = threadIdx.x;

    __shared__ float4 vlds[H_ / 4]; // 256 float4 = 4 KB
    vlds[t] = reinterpret_cast<const float4*>(v + (size_t)b * H_)[t];
    __syncthreads();

    const int wave = t >> 6;
    const int lane = t & 63;
    const int l = lc * 4 + wave;

    const float4* row =
        reinterpret_cast<const float4*>(targets + ((size_t)b * L_ + l) * H_);

    float acc = 0.f;
#pragma unroll
    for (int k = 0; k < 4; ++k) {
        const float4 tv = row[lane + 64 * k];   // 64 lanes x 16 B, coalesced
        const float4 vv = vlds[lane + 64 * k];
        acc = fmaf(tv.x, vv.x, acc);
        acc = fmaf(tv.y, vv.y, acc);
        acc = fmaf(tv.z, vv.z, acc);
        acc = fmaf(tv.w, vv.w, acc);
    }
    // 64-lane butterfly reduce
#pragma unroll
    for (int m = 32; m >= 1; m >>= 1) acc += __shfl_xor(acc, m, 64);
    if (lane == 0) e[(size_t)b * L_ + l] = acc;
}

// ---------------------------------------------------------------------------
// Kernel 3: out[b][l] = softmax over l of e[b][:]
// One block per b; 256 threads x 16 elements each, all kept in registers.
// Note: the reference's "+ bias" term is constant per (b) row and cancels
// in the softmax, so it is intentionally never computed.
// ---------------------------------------------------------------------------
__global__ __launch_bounds__(256) void softmax_kernel(const float* __restrict__ e,
                                                      float* __restrict__ out) {
    const int b = blockIdx.x;
    const int t = threadIdx.x;
    const int wave = t >> 6;
    const int lane = t & 63;

    const float4* ep = reinterpret_cast<const float4*>(e + (size_t)b * L_);
    float4 x[4];
    float mx = -INFINITY;
#pragma unroll
    for (int k = 0; k < 4; ++k) {
        x[k] = ep[t + 256 * k];
        mx = fmaxf(mx, fmaxf(fmaxf(x[k].x, x[k].y), fmaxf(x[k].z, x[k].w)));
    }

    __shared__ float redmax[4];
    __shared__ float redsum[4];

#pragma unroll
    for (int m = 32; m >= 1; m >>= 1) mx = fmaxf(mx, __shfl_xor(mx, m, 64));
    if (lane == 0) redmax[wave] = mx;
    __syncthreads();
    mx = fmaxf(fmaxf(redmax[0], redmax[1]), fmaxf(redmax[2], redmax[3]));

    float s = 0.f;
#pragma unroll
    for (int k = 0; k < 4; ++k) {
        x[k].x = expf(x[k].x - mx);
        x[k].y = expf(x[k].y - mx);
        x[k].z = expf(x[k].z - mx);
        x[k].w = expf(x[k].w - mx);
        s += x[k].x + x[k].y + x[k].z + x[k].w;
    }
#pragma unroll
    for (int m = 32; m >= 1; m >>= 1) s += __shfl_xor(s, m, 64);
    if (lane == 0) redsum[wave] = s;
    __syncthreads();
    s = redsum[0] + redsum[1] + redsum[2] + redsum[3];

    const float inv = 1.f / s;
    float4* op = reinterpret_cast<float4*>(out + (size_t)b * L_);
#pragma unroll
    for (int k = 0; k < 4; ++k) {
        float4 y = x[k];
        y.x *= inv; y.y *= inv; y.z *= inv; y.w *= inv;
        op[t + 256 * k] = y;
    }
}

// ---------------------------------------------------------------------------
// Launch
// inputs: d_in[0]=hidden [1,B,H] f32, d_in[1]=targets [B,L,H] f32,
//         d_in[2]=W [H,H] f32, d_in[3]=bias [H] f32 (unused: cancels in softmax)
// output: [B,1,L] f32
// ws layout: v [B*H] f32 @ 0, e [B*L] f32 @ B*H
// ---------------------------------------------------------------------------
extern "C" void kernel_launch(void* const* d_in, const int* in_sizes, int n_in,
                              void* d_out, int out_size, void* d_ws, size_t ws_size,
                              hipStream_t stream) {
    const float* hidden  = (const float*)d_in[0];
    const float* targets = (const float*)d_in[1];
    const float* W       = (const float*)d_in[2];
    float* out = (float*)d_out;

    float* v = (float*)d_ws;        // B*H floats
    float* e = v + (size_t)B_ * H_; // B*L floats

    hipMemsetAsync(v, 0, (size_t)B_ * H_ * sizeof(float), stream);
    vW_kernel<<<dim3(B_, H_ / 256, GSPLIT), 256, 0, stream>>>(hidden, W, v);
    energy_kernel<<<dim3(B_ * L_ / 4), 256, 0, stream>>>(targets, v, e);
    softmax_kernel<<<dim3(B_), 256, 0, stream>>>(e, out);
}